// Round 11
// baseline (490.561 us; speedup 1.0000x reference)
//
#include <hip/hip_runtime.h>

typedef __attribute__((ext_vector_type(4))) float  float4_;
typedef __attribute__((ext_vector_type(8))) short  short8;
typedef __attribute__((ext_vector_type(8))) __bf16 bf16x8;
typedef __attribute__((ext_vector_type(4))) unsigned uint4_;

__device__ inline unsigned short f2bf(float f) {
    unsigned u = __builtin_bit_cast(unsigned, f);
    u += 0x7FFFu + ((u >> 16) & 1u);          // round-to-nearest-even
    return (unsigned short)(u >> 16);
}

__device__ inline float4_ mfma16(bf16x8 a, bf16x8 b, float4_ c) {
    return __builtin_amdgcn_mfma_f32_16x16x32_bf16(a, b, c, 0, 0, 0);
}

// ---------------- one merged setup kernel (28 slots: slot 27 all-zero) ---
// packs all weights into B-fragment order + zeroes sentinel row cat[N].
// frag f = (k*ctn + ct)*ntn + nt ; elem = lane*8 + t
// value = W[k][ct*32 + (lane>>4)*8 + t][nt*16 + (lane&15)]
__device__ inline void packW_one(const float* __restrict__ src, unsigned short* __restrict__ dst,
                                 int cin, int cout, int e) {
    int f = e >> 9, i = e & 511, lane = i >> 3, t = i & 7;
    int ntn = cout >> 4, ctn = cin >> 5;
    int nt = f % ntn;
    int rest = f / ntn;
    int ct = rest % ctn;
    int k = rest / ctn;
    int c = ct * 32 + (lane >> 4) * 8 + t;
    int j = nt * 16 + (lane & 15);
    dst[e] = f2bf(src[(k * cin + c) * cout + j]);
}

__global__ void pack_all_kernel(
    const float* __restrict__ W1, const float* __restrict__ W2,
    const float* __restrict__ W3, const float* __restrict__ W4,
    const float* __restrict__ W5, const float* __restrict__ W6,
    const float* __restrict__ W7,
    unsigned short* cat, unsigned short* Wp12, unsigned short* Wp3,
    unsigned short* Wp4, unsigned short* Wp5, unsigned short* Wp6,
    unsigned short* Wp7, int N) {
    int e = blockIdx.x * 256 + threadIdx.x;
    if (e < 8192) {                                  // W1|W2 -> (64,128)
        int f = e >> 9, i = e & 511, lane = i >> 3, t = i & 7;
        int nt = f & 7, ct = f >> 3;
        int c = ct * 32 + (lane >> 4) * 8 + t;
        int j = nt * 16 + (lane & 15);
        float v = (j < 64) ? W1[c * 64 + j] : W2[c * 64 + (j - 64)];
        Wp12[e] = f2bf(v);
        return;
    }
    e -= 8192;
    if (e < 57344) { if (e < 55296) packW_one(W3, Wp3, 64, 32, e); else Wp3[e] = 0; return; }
    e -= 57344;
    if (e < 28672) { if (e < 27648) packW_one(W4, Wp4, 32, 32, e); else Wp4[e] = 0; return; }
    e -= 28672;
    if (e < 28672) { if (e < 27648) packW_one(W5, Wp5, 32, 32, e); else Wp5[e] = 0; return; }
    e -= 28672;
    if (e < 28672) { if (e < 27648) packW_one(W6, Wp6, 32, 32, e); else Wp6[e] = 0; return; }
    e -= 28672;
    if (e < 16384) { packW_one(W7, Wp7, 256, 64, e); return; }
    e -= 16384;
    if (e < 128) ((unsigned*)(cat + (size_t)N * 256))[e] = 0;   // sentinel row
}

// ---------------- plan kernel v6: ROW-MAJOR compacted slot stream --------
// Per 16-row tile t:
//   kmask[t]             union mask (conv needs popcount)
//   cidx[t][r][j]        j-th ACTIVE tap's clamped BYTE offset for row r,
//                        row stride 32 -> a lane loads ALL 28 slots as
//                        7 x dwordx4 (idx stream leaves the vm dep chain)
//   ktab[t][j]           j-th active tap id (byte); j >= c -> 27 (zero W)
__global__ __launch_bounds__(256) void plan_kernel(const int* __restrict__ nbr,
                                                   unsigned int* __restrict__ kmask,
                                                   unsigned int* __restrict__ cidx,
                                                   unsigned char* __restrict__ ktab, int N) {
    __shared__ int snb[6912];                        // 256 rows * 27 taps
    __shared__ unsigned tm[16];
    int tid = threadIdx.x;
    if (tid < 16) tm[tid] = 0u;
    __syncthreads();
    long base = (long)blockIdx.x * 6912;
#pragma unroll
    for (int i = 0; i < 27; i++) {
        int j = i * 256 + tid;
        int v = nbr[base + j];
        snb[j] = v;
        if (v >= 0) {
            unsigned r = (unsigned)j / 27u;          // local row 0..255
            unsigned k = (unsigned)j - r * 27u;
            atomicOr(&tm[r >> 4], 1u << k);
        }
    }
    __syncthreads();
    int g = tid >> 4, r = tid & 15;                  // 16 groups x 16 rows
    unsigned m = tm[g];
    int t = blockIdx.x * 16 + g;
    unsigned* cp = cidx + (size_t)t * 512 + (size_t)r * 32;   // [r][j], stride 32
    int j = 0;
#pragma unroll
    for (int k = 0; k < 27; k++) {
        if (m >> k & 1u) {
            int v = snb[(g * 16 + r) * 27 + k];
            cp[j] = (unsigned)(v < 0 ? N : v) * 512u;
            j++;
        }
    }
    for (; j < 28; j++) cp[j] = (unsigned)N * 512u;
    if (r == 0) {
        kmask[t] = m;
        unsigned char* kt = ktab + (long)t * 32;
        int jj = 0;
#pragma unroll
        for (int k = 0; k < 27; k++)
            if (m >> k & 1u) kt[jj++] = (unsigned char)k;
        for (; jj < 32; jj++) kt[jj] = 27;
    }
}

// ---------------- blk1 dual: f1|f2 = relu(LN(x@W + b)) ----------------
__global__ __launch_bounds__(256) void blk12_kernel(
    const float* __restrict__ x, unsigned short* cat,
    const unsigned short* __restrict__ Wp,
    const float* __restrict__ b1, const float* __restrict__ g1, const float* __restrict__ be1,
    const float* __restrict__ b2, const float* __restrict__ g2, const float* __restrict__ be2) {
    int tid = threadIdx.x, lane = tid & 63, wv = tid >> 6;
    int l15 = lane & 15, q = lane >> 4;
    long base = ((long)blockIdx.x * 4 + wv) * 16;

    float4_ acc[8];
#pragma unroll
    for (int i = 0; i < 8; i++) acc[i] = (float4_){0.f, 0.f, 0.f, 0.f};

#pragma unroll
    for (int kt = 0; kt < 2; kt++) {
        const float* xp = x + (base + l15) * 64 + kt * 32 + q * 8;
        float4_ f0 = *(const float4_*)xp;
        float4_ f1 = *(const float4_*)(xp + 4);
        short8 as;
        as[0] = (short)f2bf(f0[0]); as[1] = (short)f2bf(f0[1]);
        as[2] = (short)f2bf(f0[2]); as[3] = (short)f2bf(f0[3]);
        as[4] = (short)f2bf(f1[0]); as[5] = (short)f2bf(f1[1]);
        as[6] = (short)f2bf(f1[2]); as[7] = (short)f2bf(f1[3]);
        bf16x8 a = __builtin_bit_cast(bf16x8, as);
        const unsigned short* wp = Wp + (size_t)kt * 8 * 512;
#pragma unroll
        for (int nt = 0; nt < 8; nt++) {
            bf16x8 w = *(const bf16x8*)(wp + nt * 512 + lane * 8);
            acc[nt] = mfma16(a, w, acc[nt]);
        }
    }

    float bc[8], gc[8], bec[8];
#pragma unroll
    for (int nt = 0; nt < 8; nt++) {
        int j = nt * 16 + l15;
        if (j < 64) { bc[nt] = b1[j]; gc[nt] = g1[j]; bec[nt] = be1[j]; }
        else        { bc[nt] = b2[j - 64]; gc[nt] = g2[j - 64]; bec[nt] = be2[j - 64]; }
    }

#pragma unroll
    for (int r = 0; r < 4; r++) {
        long row = base + q * 4 + r;
        float v[8], s0 = 0.f, s1 = 0.f, q0 = 0.f, q1 = 0.f;
#pragma unroll
        for (int nt = 0; nt < 4; nt++) { v[nt] = acc[nt][r] + bc[nt]; s0 += v[nt]; q0 += v[nt] * v[nt]; }
#pragma unroll
        for (int nt = 4; nt < 8; nt++) { v[nt] = acc[nt][r] + bc[nt]; s1 += v[nt]; q1 += v[nt] * v[nt]; }
#pragma unroll
        for (int m = 1; m < 16; m <<= 1) {
            s0 += __shfl_xor(s0, m); q0 += __shfl_xor(q0, m);
            s1 += __shfl_xor(s1, m); q1 += __shfl_xor(q1, m);
        }
        float mu0 = s0 * (1.f / 64), var0 = q0 * (1.f / 64) - mu0 * mu0, inv0 = rsqrtf(var0 + 1e-5f);
        float mu1 = s1 * (1.f / 64), var1 = q1 * (1.f / 64) - mu1 * mu1, inv1 = rsqrtf(var1 + 1e-5f);
        unsigned short* cp = cat + row * 256;
#pragma unroll
        for (int nt = 0; nt < 4; nt++) {
            float y = fmaxf((v[nt] - mu0) * inv0 * gc[nt] + bec[nt], 0.f);
            cp[nt * 16 + l15] = f2bf(y);
        }
#pragma unroll
        for (int nt = 4; nt < 8; nt++) {
            float y = fmaxf((v[nt] - mu1) * inv1 * gc[nt] + bec[nt], 0.f);
            cp[nt * 16 + l15] = f2bf(y);
        }
    }
}

// ---------------- sparse conv: branchless core, deep lead, upfront idx ---
// r10 lesson: branchless helped (66->58) but D=4 lead (~200cy) covers only
// half the ~400-500cy L3 gather latency. v11: all 28 slot offsets loaded
// upfront into registers (7 x dwordx4; idx leaves the vm dep chain), gather
// lead D=8 (CT=1) / D=5 (CT=2) ~= full latency, weight lead 3 (CT=1).
// Sentinel slots (j >= c) read the zero row / zero W block 27 -> exact 0.
template <int CT, int D, int NS>
__device__ __forceinline__ void conv_core(
    float4_ acc[2], const char* catb, const uint4_* iv,
    const unsigned* kt8, const unsigned short* wl) {
    bf16x8 f[D + 1][CT];
    constexpr int WR = (CT == 1) ? 4 : 3;            // weight ring size
    constexpr int WL = WR - 1;                       // weight lead
    bf16x8 wr[WR][CT][2];

#define KB(k) ((kt8[(k) >> 2] >> (((k) & 3) * 8)) & 0xFFu)
#define IDX(j) (iv[(j) >> 2][(j) & 3])

    // ---- prologue: weights slots 0..WL-1, gathers slots 0..D-1 ----
#pragma unroll
    for (int kk = 0; kk < WL; kk++) {
        unsigned wo = KB(kk) * (CT * 1024u);
#pragma unroll
        for (int ct = 0; ct < CT; ct++)
#pragma unroll
            for (int nt = 0; nt < 2; nt++)
                wr[kk][ct][nt] = *(const bf16x8*)(wl + wo + (ct * 2 + nt) * 512);
    }
#pragma unroll
    for (int j = 0; j < D; j++) {
#pragma unroll
        for (int ct = 0; ct < CT; ct++)
            f[j][ct] = *(const bf16x8*)(catb + (size_t)IDX(j) + ct * 64);
    }

    // ---- main loop: NS static slots, zero branches ----
#pragma unroll
    for (int k = 0; k < NS; k++) {
        if (k + WL < NS) {                           // weights for slot k+WL
            unsigned wo = KB(k + WL) * (CT * 1024u);
#pragma unroll
            for (int ct = 0; ct < CT; ct++)
#pragma unroll
                for (int nt = 0; nt < 2; nt++)
                    wr[(k + WL) % WR][ct][nt] = *(const bf16x8*)(wl + wo + (ct * 2 + nt) * 512);
        }
        if (k + D < NS) {                            // gathers for slot k+D
            unsigned voff = IDX(k + D);
#pragma unroll
            for (int ct = 0; ct < CT; ct++)
                f[(k + D) % (D + 1)][ct] = *(const bf16x8*)(catb + (size_t)voff + ct * 64);
        }
#pragma unroll
        for (int ct = 0; ct < CT; ct++) {            // MFMA for slot k
            acc[0] = mfma16(f[k % (D + 1)][ct], wr[k % WR][ct][0], acc[0]);
            acc[1] = mfma16(f[k % (D + 1)][ct], wr[k % WR][ct][1], acc[1]);
        }
    }
#undef IDX
#undef KB
}

template <int CT, int D>
__global__ __launch_bounds__(256) void conv_kernel(
    unsigned short* cat, const unsigned int* __restrict__ cidx,
    const unsigned char* __restrict__ ktab,
    const unsigned int* __restrict__ kmask,
    const unsigned short* __restrict__ Wp,
    const float* __restrict__ bb, const float* __restrict__ gg, const float* __restrict__ bee,
    int in_off, int out_off, int N) {
    int tid = threadIdx.x, lane = tid & 63, wv = tid >> 6;
    int l15 = lane & 15, q = lane >> 4;

    // bijective XCD-chunked swizzle (gridDim.x % 8 == 0)
    int cpx = (int)(gridDim.x >> 3);
    int sb = ((int)blockIdx.x & 7) * cpx + ((int)blockIdx.x >> 3);
    int t = sb * 4 + wv;
    long base = (long)t * 16;

    unsigned m = __builtin_amdgcn_readfirstlane(kmask[t]);
    int trips = (__popc(m) + 3) >> 2;                // 1..7 (self tap => c>=1)

    const char* catb = (const char*)cat + (size_t)in_off * 2 + q * 16;
    const unsigned short* wl = Wp + lane * 8;

    // all 28 slot offsets for this lane's row, upfront
    const unsigned* cxr = cidx + (size_t)t * 512 + (size_t)l15 * 32;
    uint4_ iv[7];
#pragma unroll
    for (int i = 0; i < 7; i++) iv[i] = *(const uint4_*)(cxr + i * 4);

    uint4_ kv0 = *(const uint4_*)(ktab + (long)t * 32);
    uint4_ kv1 = *(const uint4_*)(ktab + (long)t * 32 + 16);
    unsigned kt8[8] = {kv0[0], kv0[1], kv0[2], kv0[3], kv1[0], kv1[1], kv1[2], kv1[3]};

    float4_ acc[2];
    acc[0] = (float4_){0.f, 0.f, 0.f, 0.f};
    acc[1] = (float4_){0.f, 0.f, 0.f, 0.f};

    switch (trips) {
        case 1: conv_core<CT, D, 4>(acc, catb, iv, kt8, wl); break;
        case 2: conv_core<CT, D, 8>(acc, catb, iv, kt8, wl); break;
        case 3: conv_core<CT, D, 12>(acc, catb, iv, kt8, wl); break;
        case 4: conv_core<CT, D, 16>(acc, catb, iv, kt8, wl); break;
        case 5: conv_core<CT, D, 20>(acc, catb, iv, kt8, wl); break;
        case 6: conv_core<CT, D, 24>(acc, catb, iv, kt8, wl); break;
        default: conv_core<CT, D, 28>(acc, catb, iv, kt8, wl); break;
    }

    // ---- epilogue: bias + LN(32ch) + relu + store ----
    float b0c = bb[l15], b1c = bb[16 + l15];
    float g0c = gg[l15], g1c = gg[16 + l15];
    float be0c = bee[l15], be1c = bee[16 + l15];

#pragma unroll
    for (int r = 0; r < 4; r++) {
        long row = base + q * 4 + r;
        float v0 = acc[0][r] + b0c;
        float v1 = acc[1][r] + b1c;
        float s = v0 + v1, sq = v0 * v0 + v1 * v1;
#pragma unroll
        for (int mh = 1; mh < 16; mh <<= 1) { s += __shfl_xor(s, mh); sq += __shfl_xor(sq, mh); }
        float mu = s * (1.f / 32), var = sq * (1.f / 32) - mu * mu, inv = rsqrtf(var + 1e-5f);
        float y0 = fmaxf((v0 - mu) * inv * g0c + be0c, 0.f);
        float y1 = fmaxf((v1 - mu) * inv * g1c + be1c, 0.f);
        unsigned short* cp = cat + row * 256 + out_off;
        cp[l15] = f2bf(y0);
        cp[16 + l15] = f2bf(y1);
    }
}

// ---------------- final blk1: out = relu(LN(cat@W7 + b7)) ----------------
__global__ __launch_bounds__(256) void blk7_kernel(
    const unsigned short* __restrict__ cat, const unsigned short* __restrict__ Wp,
    const float* __restrict__ b, const float* __restrict__ g, const float* __restrict__ be,
    float* __restrict__ out) {
    int tid = threadIdx.x, lane = tid & 63, wv = tid >> 6;
    int l15 = lane & 15, q = lane >> 4;
    long base = ((long)blockIdx.x * 4 + wv) * 16;

    float4_ acc[4];
#pragma unroll
    for (int i = 0; i < 4; i++) acc[i] = (float4_){0.f, 0.f, 0.f, 0.f};

#pragma unroll
    for (int kt = 0; kt < 8; kt++) {
        bf16x8 a = *(const bf16x8*)(cat + (base + l15) * 256 + kt * 32 + q * 8);
        const unsigned short* wp = Wp + (size_t)kt * 4 * 512;
#pragma unroll
        for (int nt = 0; nt < 4; nt++) {
            bf16x8 w = *(const bf16x8*)(wp + nt * 512 + lane * 8);
            acc[nt] = mfma16(a, w, acc[nt]);
        }
    }

    float bc[4], gc[4], bec[4];
#pragma unroll
    for (int nt = 0; nt < 4; nt++) {
        int j = nt * 16 + l15;
        bc[nt] = b[j]; gc[nt] = g[j]; bec[nt] = be[j];
    }

#pragma unroll
    for (int r = 0; r < 4; r++) {
        long row = base + q * 4 + r;
        float v[4], s = 0.f, sq = 0.f;
#pragma unroll
        for (int nt = 0; nt < 4; nt++) { v[nt] = acc[nt][r] + bc[nt]; s += v[nt]; sq += v[nt] * v[nt]; }
#pragma unroll
        for (int m = 1; m < 16; m <<= 1) { s += __shfl_xor(s, m); sq += __shfl_xor(sq, m); }
        float mu = s * (1.f / 64), var = sq * (1.f / 64) - mu * mu, inv = rsqrtf(var + 1e-5f);
#pragma unroll
        for (int nt = 0; nt < 4; nt++) {
            float y = fmaxf((v[nt] - mu) * inv * gc[nt] + bec[nt], 0.f);
            out[row * 64 + nt * 16 + l15] = y;
        }
    }
}

extern "C" void kernel_launch(void* const* d_in, const int* in_sizes, int n_in,
                              void* d_out, int out_size, void* d_ws, size_t ws_size,
                              hipStream_t stream) {
    const int N = in_sizes[0] / 64;   // 262144

    const float* x   = (const float*)d_in[0];
    const int*   nbr = (const int*)d_in[1];
    const float* W1 = (const float*)d_in[2];
    const float* b1 = (const float*)d_in[3];
    const float* g1 = (const float*)d_in[4];
    const float* be1 = (const float*)d_in[5];
    const float* W2 = (const float*)d_in[6];
    const float* b2 = (const float*)d_in[7];
    const float* g2 = (const float*)d_in[8];
    const float* be2 = (const float*)d_in[9];
    const float* W3 = (const float*)d_in[10];
    const float* b3 = (const float*)d_in[11];
    const float* g3 = (const float*)d_in[12];
    const float* be3 = (const float*)d_in[13];
    const float* W4 = (const float*)d_in[14];
    const float* b4 = (const float*)d_in[15];
    const float* g4 = (const float*)d_in[16];
    const float* be4 = (const float*)d_in[17];
    const float* W5 = (const float*)d_in[18];
    const float* b5 = (const float*)d_in[19];
    const float* g5 = (const float*)d_in[20];
    const float* be5 = (const float*)d_in[21];
    const float* W6 = (const float*)d_in[22];
    const float* b6 = (const float*)d_in[23];
    const float* g6 = (const float*)d_in[24];
    const float* be6 = (const float*)d_in[25];
    const float* W7 = (const float*)d_in[26];
    const float* b7 = (const float*)d_in[27];
    const float* g7 = (const float*)d_in[28];
    const float* be7 = (const float*)d_in[29];

    unsigned short* ws   = (unsigned short*)d_ws;
    unsigned short* cat  = ws;                               // (N+1)*256 bf16
    unsigned short* Wp12 = cat + (size_t)(N + 1) * 256;      // 8192
    unsigned short* Wp3  = Wp12 + 8192;                      // 28*2*2*512 = 57344 (slot 27 zero)
    unsigned short* Wp4  = Wp3 + 57344;                      // 28*1*2*512 = 28672
    unsigned short* Wp5  = Wp4 + 28672;
    unsigned short* Wp6  = Wp5 + 28672;
    unsigned short* Wp7  = Wp6 + 28672;                      // 8*4*512 = 16384
    unsigned int*   kmask = (unsigned int*)(Wp7 + 16384);    // N/16 uints
    unsigned int*   cidx  = kmask + N / 16;                  // N/16 * 512 uints
    unsigned char*  ktab  = (unsigned char*)(cidx + (size_t)(N / 16) * 512);  // N/16 * 32 B

    pack_all_kernel<<<657, 256, 0, stream>>>(W1, W2, W3, W4, W5, W6, W7,
                                             cat, Wp12, Wp3, Wp4, Wp5, Wp6, Wp7, N);
    plan_kernel<<<N / 256, 256, 0, stream>>>(nbr, kmask, cidx, ktab, N);

    blk12_kernel<<<N / 64, 256, 0, stream>>>(x, cat, Wp12, b1, g1, be1, b2, g2, be2);
    conv_kernel<2, 5><<<N / 64, 256, 0, stream>>>(cat, cidx, ktab, kmask, Wp3, b3, g3, be3, 64, 128, N);
    conv_kernel<1, 8><<<N / 64, 256, 0, stream>>>(cat, cidx, ktab, kmask, Wp4, b4, g4, be4, 128, 160, N);
    conv_kernel<1, 8><<<N / 64, 256, 0, stream>>>(cat, cidx, ktab, kmask, Wp5, b5, g5, be5, 160, 192, N);
    conv_kernel<1, 8><<<N / 64, 256, 0, stream>>>(cat, cidx, ktab, kmask, Wp6, b6, g6, be6, 192, 224, N);
    blk7_kernel<<<N / 64, 256, 0, stream>>>(cat, Wp7, b7, g7, be7, (float*)d_out);
}

// Round 12
// 454.190 us; speedup vs baseline: 1.0801x; 1.0801x over previous
//
#include <hip/hip_runtime.h>

typedef __attribute__((ext_vector_type(4))) float  float4_;
typedef __attribute__((ext_vector_type(8))) short  short8;
typedef __attribute__((ext_vector_type(8))) __bf16 bf16x8;
typedef __attribute__((ext_vector_type(4))) unsigned uint4_;

__device__ inline unsigned short f2bf(float f) {
    unsigned u = __builtin_bit_cast(unsigned, f);
    u += 0x7FFFu + ((u >> 16) & 1u);          // round-to-nearest-even
    return (unsigned short)(u >> 16);
}

__device__ inline float4_ mfma16(bf16x8 a, bf16x8 b, float4_ c) {
    return __builtin_amdgcn_mfma_f32_16x16x32_bf16(a, b, c, 0, 0, 0);
}

// ---------------- one merged setup kernel (28 slots: slot 27 all-zero) ---
// packs all weights into B-fragment order + zeroes sentinel row cat[N].
// frag f = (k*ctn + ct)*ntn + nt ; elem = lane*8 + t
// value = W[k][ct*32 + (lane>>4)*8 + t][nt*16 + (lane&15)]
__device__ inline void packW_one(const float* __restrict__ src, unsigned short* __restrict__ dst,
                                 int cin, int cout, int e) {
    int f = e >> 9, i = e & 511, lane = i >> 3, t = i & 7;
    int ntn = cout >> 4, ctn = cin >> 5;
    int nt = f % ntn;
    int rest = f / ntn;
    int ct = rest % ctn;
    int k = rest / ctn;
    int c = ct * 32 + (lane >> 4) * 8 + t;
    int j = nt * 16 + (lane & 15);
    dst[e] = f2bf(src[(k * cin + c) * cout + j]);
}

__global__ void pack_all_kernel(
    const float* __restrict__ W1, const float* __restrict__ W2,
    const float* __restrict__ W3, const float* __restrict__ W4,
    const float* __restrict__ W5, const float* __restrict__ W6,
    const float* __restrict__ W7,
    unsigned short* cat, unsigned short* Wp12, unsigned short* Wp3,
    unsigned short* Wp4, unsigned short* Wp5, unsigned short* Wp6,
    unsigned short* Wp7, int N) {
    int e = blockIdx.x * 256 + threadIdx.x;
    if (e < 8192) {                                  // W1|W2 -> (64,128)
        int f = e >> 9, i = e & 511, lane = i >> 3, t = i & 7;
        int nt = f & 7, ct = f >> 3;
        int c = ct * 32 + (lane >> 4) * 8 + t;
        int j = nt * 16 + (lane & 15);
        float v = (j < 64) ? W1[c * 64 + j] : W2[c * 64 + (j - 64)];
        Wp12[e] = f2bf(v);
        return;
    }
    e -= 8192;
    if (e < 57344) { if (e < 55296) packW_one(W3, Wp3, 64, 32, e); else Wp3[e] = 0; return; }
    e -= 57344;
    if (e < 28672) { if (e < 27648) packW_one(W4, Wp4, 32, 32, e); else Wp4[e] = 0; return; }
    e -= 28672;
    if (e < 28672) { if (e < 27648) packW_one(W5, Wp5, 32, 32, e); else Wp5[e] = 0; return; }
    e -= 28672;
    if (e < 28672) { if (e < 27648) packW_one(W6, Wp6, 32, 32, e); else Wp6[e] = 0; return; }
    e -= 28672;
    if (e < 16384) { packW_one(W7, Wp7, 256, 64, e); return; }
    e -= 16384;
    if (e < 128) ((unsigned*)(cat + (size_t)N * 256))[e] = 0;   // sentinel row
}

// ---------------- plan kernel v7: LDS-staged, COALESCED output -----------
// Same outputs as r10's v5 (slot-major cidx [t][j][r] stride-448, kmask,
// ktab), but the compacted table is built in LDS and written out with a
// flat fully-coalesced 28-iteration copy (v5's global writes were 16-lane
// divergent scattered dwords — suspected ~50us of the ~200us non-conv gap).
__global__ __launch_bounds__(256) void plan_kernel(const int* __restrict__ nbr,
                                                   unsigned int* __restrict__ kmask,
                                                   unsigned int* __restrict__ cidx,
                                                   unsigned char* __restrict__ ktab, int N) {
    __shared__ int snb[6912];                        // 256 rows * 27 taps
    __shared__ unsigned sout[7168];                  // 16 tiles * 448 dwords
    __shared__ unsigned tm[16];
    int tid = threadIdx.x;
    if (tid < 16) tm[tid] = 0u;
    __syncthreads();
    long base = (long)blockIdx.x * 6912;
#pragma unroll
    for (int i = 0; i < 27; i++) {
        int j = i * 256 + tid;
        int v = nbr[base + j];
        snb[j] = v;
        if (v >= 0) {
            unsigned r = (unsigned)j / 27u;          // local row 0..255
            unsigned k = (unsigned)j - r * 27u;
            atomicOr(&tm[r >> 4], 1u << k);
        }
    }
    __syncthreads();
    int g = tid >> 4, r = tid & 15;                  // 16 groups x 16 rows
    unsigned m = tm[g];
    unsigned* sp = sout + g * 448;
    int j = 0;
#pragma unroll
    for (int k = 0; k < 27; k++) {
        if (m >> k & 1u) {
            int v = snb[(g * 16 + r) * 27 + k];
            sp[j * 16 + r] = (unsigned)(v < 0 ? N : v) * 512u;
            j++;
        }
    }
    for (; j < 28; j++) sp[j * 16 + r] = (unsigned)N * 512u;
    if (r == 0) {
        int t = blockIdx.x * 16 + g;
        kmask[t] = m;
        unsigned char* kt = ktab + (long)t * 32;
        int jj = 0;
#pragma unroll
        for (int k = 0; k < 27; k++)
            if (m >> k & 1u) kt[jj++] = (unsigned char)k;
        for (; jj < 32; jj++) kt[jj] = 27;
    }
    __syncthreads();
    unsigned* cp = cidx + (size_t)blockIdx.x * 7168;
#pragma unroll
    for (int i = 0; i < 28; i++) cp[i * 256 + tid] = sout[i * 256 + tid];
}

// ---------------- blk1 dual: f1|f2 = relu(LN(x@W + b)) ----------------
__global__ __launch_bounds__(256) void blk12_kernel(
    const float* __restrict__ x, unsigned short* cat,
    const unsigned short* __restrict__ Wp,
    const float* __restrict__ b1, const float* __restrict__ g1, const float* __restrict__ be1,
    const float* __restrict__ b2, const float* __restrict__ g2, const float* __restrict__ be2) {
    int tid = threadIdx.x, lane = tid & 63, wv = tid >> 6;
    int l15 = lane & 15, q = lane >> 4;
    long base = ((long)blockIdx.x * 4 + wv) * 16;

    float4_ acc[8];
#pragma unroll
    for (int i = 0; i < 8; i++) acc[i] = (float4_){0.f, 0.f, 0.f, 0.f};

#pragma unroll
    for (int kt = 0; kt < 2; kt++) {
        const float* xp = x + (base + l15) * 64 + kt * 32 + q * 8;
        float4_ f0 = *(const float4_*)xp;
        float4_ f1 = *(const float4_*)(xp + 4);
        short8 as;
        as[0] = (short)f2bf(f0[0]); as[1] = (short)f2bf(f0[1]);
        as[2] = (short)f2bf(f0[2]); as[3] = (short)f2bf(f0[3]);
        as[4] = (short)f2bf(f1[0]); as[5] = (short)f2bf(f1[1]);
        as[6] = (short)f2bf(f1[2]); as[7] = (short)f2bf(f1[3]);
        bf16x8 a = __builtin_bit_cast(bf16x8, as);
        const unsigned short* wp = Wp + (size_t)kt * 8 * 512;
#pragma unroll
        for (int nt = 0; nt < 8; nt++) {
            bf16x8 w = *(const bf16x8*)(wp + nt * 512 + lane * 8);
            acc[nt] = mfma16(a, w, acc[nt]);
        }
    }

    float bc[8], gc[8], bec[8];
#pragma unroll
    for (int nt = 0; nt < 8; nt++) {
        int j = nt * 16 + l15;
        if (j < 64) { bc[nt] = b1[j]; gc[nt] = g1[j]; bec[nt] = be1[j]; }
        else        { bc[nt] = b2[j - 64]; gc[nt] = g2[j - 64]; bec[nt] = be2[j - 64]; }
    }

#pragma unroll
    for (int r = 0; r < 4; r++) {
        long row = base + q * 4 + r;
        float v[8], s0 = 0.f, s1 = 0.f, q0 = 0.f, q1 = 0.f;
#pragma unroll
        for (int nt = 0; nt < 4; nt++) { v[nt] = acc[nt][r] + bc[nt]; s0 += v[nt]; q0 += v[nt] * v[nt]; }
#pragma unroll
        for (int nt = 4; nt < 8; nt++) { v[nt] = acc[nt][r] + bc[nt]; s1 += v[nt]; q1 += v[nt] * v[nt]; }
#pragma unroll
        for (int m = 1; m < 16; m <<= 1) {
            s0 += __shfl_xor(s0, m); q0 += __shfl_xor(q0, m);
            s1 += __shfl_xor(s1, m); q1 += __shfl_xor(q1, m);
        }
        float mu0 = s0 * (1.f / 64), var0 = q0 * (1.f / 64) - mu0 * mu0, inv0 = rsqrtf(var0 + 1e-5f);
        float mu1 = s1 * (1.f / 64), var1 = q1 * (1.f / 64) - mu1 * mu1, inv1 = rsqrtf(var1 + 1e-5f);
        unsigned short* cp = cat + row * 256;
#pragma unroll
        for (int nt = 0; nt < 4; nt++) {
            float y = fmaxf((v[nt] - mu0) * inv0 * gc[nt] + bec[nt], 0.f);
            cp[nt * 16 + l15] = f2bf(y);
        }
#pragma unroll
        for (int nt = 4; nt < 8; nt++) {
            float y = fmaxf((v[nt] - mu1) * inv1 * gc[nt] + bec[nt], 0.f);
            cp[nt * 16 + l15] = f2bf(y);
        }
    }
}

// ---------------- sparse conv: r10 branchless compacted core (reverted) --
// r11 falsified the deep-lead theory (D=8 + upfront idx regressed by its
// own added traffic) -> r10 structure restored verbatim: compacted slot
// stream, branch-free unrolled core, slot-major cidx (64B line per slot),
// cv ring lead D+2, weight ring lead 2. Sentinel slots (j >= c) read the
// zero row / zero weight block 27 -> contribute exactly 0.
template <int CT, int D, int NS>
__device__ __forceinline__ void conv_core(
    float4_ acc[2], const char* catb, const unsigned* cx,
    const unsigned* kt8, const unsigned short* wl) {
    bf16x8 f[D + 1][CT];
    bf16x8 wr[3][CT][2];
    unsigned cv[3];

#define KB(k) ((kt8[(k) >> 2] >> (((k) & 3) * 8)) & 0xFFu)

    unsigned cv0[D + 2];
#pragma unroll
    for (int j = 0; j < D + 2; j++) cv0[j] = cx[j * 16];

#pragma unroll
    for (int kk = 0; kk < 2; kk++) {
        unsigned wo = KB(kk) * (CT * 1024u);
#pragma unroll
        for (int ct = 0; ct < CT; ct++)
#pragma unroll
            for (int nt = 0; nt < 2; nt++)
                wr[kk][ct][nt] = *(const bf16x8*)(wl + wo + (ct * 2 + nt) * 512);
    }

#pragma unroll
    for (int j = 0; j < D; j++) {
#pragma unroll
        for (int ct = 0; ct < CT; ct++)
            f[j][ct] = *(const bf16x8*)(catb + (size_t)cv0[j] + ct * 64);
    }
    cv[D % 3] = cv0[D];
    cv[(D + 1) % 3] = cv0[D + 1];

#pragma unroll
    for (int k = 0; k < NS; k++) {
        if (k + 2 < NS) {                            // weights for slot k+2
            unsigned wo = KB(k + 2) * (CT * 1024u);
#pragma unroll
            for (int ct = 0; ct < CT; ct++)
#pragma unroll
                for (int nt = 0; nt < 2; nt++)
                    wr[(k + 2) % 3][ct][nt] = *(const bf16x8*)(wl + wo + (ct * 2 + nt) * 512);
        }
        if (k + D < NS) {                            // gathers for slot k+D
            unsigned voff = cv[(k + D) % 3];
#pragma unroll
            for (int ct = 0; ct < CT; ct++)
                f[(k + D) % (D + 1)][ct] = *(const bf16x8*)(catb + (size_t)voff + ct * 64);
        }
        if (k + D + 2 < NS) cv[(k + D + 2) % 3] = cx[(k + D + 2) * 16];
#pragma unroll
        for (int ct = 0; ct < CT; ct++) {            // MFMA for slot k
            acc[0] = mfma16(f[k % (D + 1)][ct], wr[k % 3][ct][0], acc[0]);
            acc[1] = mfma16(f[k % (D + 1)][ct], wr[k % 3][ct][1], acc[1]);
        }
    }
#undef KB
}

template <int CT, int D>
__global__ __launch_bounds__(256) void conv_kernel(
    unsigned short* cat, const unsigned int* __restrict__ cidx,
    const unsigned char* __restrict__ ktab,
    const unsigned int* __restrict__ kmask,
    const unsigned short* __restrict__ Wp,
    const float* __restrict__ bb, const float* __restrict__ gg, const float* __restrict__ bee,
    int in_off, int out_off, int N) {
    int tid = threadIdx.x, lane = tid & 63, wv = tid >> 6;
    int l15 = lane & 15, q = lane >> 4;

    // bijective XCD-chunked swizzle (gridDim.x % 8 == 0)
    int cpx = (int)(gridDim.x >> 3);
    int sb = ((int)blockIdx.x & 7) * cpx + ((int)blockIdx.x >> 3);
    int t = sb * 4 + wv;
    long base = (long)t * 16;

    unsigned m = __builtin_amdgcn_readfirstlane(kmask[t]);
    int trips = (__popc(m) + 3) >> 2;                // 1..7 (self tap => c>=1)

    const char* catb = (const char*)cat + (size_t)in_off * 2 + q * 16;
    const unsigned* cx = cidx + (long)t * 448 + l15;
    const unsigned short* wl = Wp + lane * 8;

    uint4_ kv0 = *(const uint4_*)(ktab + (long)t * 32);
    uint4_ kv1 = *(const uint4_*)(ktab + (long)t * 32 + 16);
    unsigned kt8[8] = {kv0[0], kv0[1], kv0[2], kv0[3], kv1[0], kv1[1], kv1[2], kv1[3]};

    float4_ acc[2];
    acc[0] = (float4_){0.f, 0.f, 0.f, 0.f};
    acc[1] = (float4_){0.f, 0.f, 0.f, 0.f};

    switch (trips) {
        case 1: conv_core<CT, D, 4>(acc, catb, cx, kt8, wl); break;
        case 2: conv_core<CT, D, 8>(acc, catb, cx, kt8, wl); break;
        case 3: conv_core<CT, D, 12>(acc, catb, cx, kt8, wl); break;
        case 4: conv_core<CT, D, 16>(acc, catb, cx, kt8, wl); break;
        case 5: conv_core<CT, D, 20>(acc, catb, cx, kt8, wl); break;
        case 6: conv_core<CT, D, 24>(acc, catb, cx, kt8, wl); break;
        default: conv_core<CT, D, 28>(acc, catb, cx, kt8, wl); break;
    }

    // ---- epilogue: bias + LN(32ch) + relu + store ----
    float b0c = bb[l15], b1c = bb[16 + l15];
    float g0c = gg[l15], g1c = gg[16 + l15];
    float be0c = bee[l15], be1c = bee[16 + l15];

#pragma unroll
    for (int r = 0; r < 4; r++) {
        long row = base + q * 4 + r;
        float v0 = acc[0][r] + b0c;
        float v1 = acc[1][r] + b1c;
        float s = v0 + v1, sq = v0 * v0 + v1 * v1;
#pragma unroll
        for (int mh = 1; mh < 16; mh <<= 1) { s += __shfl_xor(s, mh); sq += __shfl_xor(sq, mh); }
        float mu = s * (1.f / 32), var = sq * (1.f / 32) - mu * mu, inv = rsqrtf(var + 1e-5f);
        float y0 = fmaxf((v0 - mu) * inv * g0c + be0c, 0.f);
        float y1 = fmaxf((v1 - mu) * inv * g1c + be1c, 0.f);
        unsigned short* cp = cat + row * 256 + out_off;
        cp[l15] = f2bf(y0);
        cp[16 + l15] = f2bf(y1);
    }
}

// ---------------- final blk1: out = relu(LN(cat@W7 + b7)) ----------------
__global__ __launch_bounds__(256) void blk7_kernel(
    const unsigned short* __restrict__ cat, const unsigned short* __restrict__ Wp,
    const float* __restrict__ b, const float* __restrict__ g, const float* __restrict__ be,
    float* __restrict__ out) {
    int tid = threadIdx.x, lane = tid & 63, wv = tid >> 6;
    int l15 = lane & 15, q = lane >> 4;
    long base = ((long)blockIdx.x * 4 + wv) * 16;

    float4_ acc[4];
#pragma unroll
    for (int i = 0; i < 4; i++) acc[i] = (float4_){0.f, 0.f, 0.f, 0.f};

#pragma unroll
    for (int kt = 0; kt < 8; kt++) {
        bf16x8 a = *(const bf16x8*)(cat + (base + l15) * 256 + kt * 32 + q * 8);
        const unsigned short* wp = Wp + (size_t)kt * 4 * 512;
#pragma unroll
        for (int nt = 0; nt < 4; nt++) {
            bf16x8 w = *(const bf16x8*)(wp + nt * 512 + lane * 8);
            acc[nt] = mfma16(a, w, acc[nt]);
        }
    }

    float bc[4], gc[4], bec[4];
#pragma unroll
    for (int nt = 0; nt < 4; nt++) {
        int j = nt * 16 + l15;
        bc[nt] = b[j]; gc[nt] = g[j]; bec[nt] = be[j];
    }

#pragma unroll
    for (int r = 0; r < 4; r++) {
        long row = base + q * 4 + r;
        float v[4], s = 0.f, sq = 0.f;
#pragma unroll
        for (int nt = 0; nt < 4; nt++) { v[nt] = acc[nt][r] + bc[nt]; s += v[nt]; sq += v[nt] * v[nt]; }
#pragma unroll
        for (int m = 1; m < 16; m <<= 1) { s += __shfl_xor(s, m); sq += __shfl_xor(sq, m); }
        float mu = s * (1.f / 64), var = sq * (1.f / 64) - mu * mu, inv = rsqrtf(var + 1e-5f);
#pragma unroll
        for (int nt = 0; nt < 4; nt++) {
            float y = fmaxf((v[nt] - mu) * inv * gc[nt] + bec[nt], 0.f);
            out[row * 64 + nt * 16 + l15] = y;
        }
    }
}

extern "C" void kernel_launch(void* const* d_in, const int* in_sizes, int n_in,
                              void* d_out, int out_size, void* d_ws, size_t ws_size,
                              hipStream_t stream) {
    const int N = in_sizes[0] / 64;   // 262144

    const float* x   = (const float*)d_in[0];
    const int*   nbr = (const int*)d_in[1];
    const float* W1 = (const float*)d_in[2];
    const float* b1 = (const float*)d_in[3];
    const float* g1 = (const float*)d_in[4];
    const float* be1 = (const float*)d_in[5];
    const float* W2 = (const float*)d_in[6];
    const float* b2 = (const float*)d_in[7];
    const float* g2 = (const float*)d_in[8];
    const float* be2 = (const float*)d_in[9];
    const float* W3 = (const float*)d_in[10];
    const float* b3 = (const float*)d_in[11];
    const float* g3 = (const float*)d_in[12];
    const float* be3 = (const float*)d_in[13];
    const float* W4 = (const float*)d_in[14];
    const float* b4 = (const float*)d_in[15];
    const float* g4 = (const float*)d_in[16];
    const float* be4 = (const float*)d_in[17];
    const float* W5 = (const float*)d_in[18];
    const float* b5 = (const float*)d_in[19];
    const float* g5 = (const float*)d_in[20];
    const float* be5 = (const float*)d_in[21];
    const float* W6 = (const float*)d_in[22];
    const float* b6 = (const float*)d_in[23];
    const float* g6 = (const float*)d_in[24];
    const float* be6 = (const float*)d_in[25];
    const float* W7 = (const float*)d_in[26];
    const float* b7 = (const float*)d_in[27];
    const float* g7 = (const float*)d_in[28];
    const float* be7 = (const float*)d_in[29];

    unsigned short* ws   = (unsigned short*)d_ws;
    unsigned short* cat  = ws;                               // (N+1)*256 bf16
    unsigned short* Wp12 = cat + (size_t)(N + 1) * 256;      // 8192
    unsigned short* Wp3  = Wp12 + 8192;                      // 28*2*2*512 = 57344 (slot 27 zero)
    unsigned short* Wp4  = Wp3 + 57344;                      // 28*1*2*512 = 28672
    unsigned short* Wp5  = Wp4 + 28672;
    unsigned short* Wp6  = Wp5 + 28672;
    unsigned short* Wp7  = Wp6 + 28672;                      // 8*4*512 = 16384
    unsigned int*   kmask = (unsigned int*)(Wp7 + 16384);    // N/16 uints
    unsigned int*   cidx  = kmask + N / 16;                  // N/16 * 448 uints
    unsigned char*  ktab  = (unsigned char*)(cidx + (size_t)(N / 16) * 448);  // N/16 * 32 B

    pack_all_kernel<<<657, 256, 0, stream>>>(W1, W2, W3, W4, W5, W6, W7,
                                             cat, Wp12, Wp3, Wp4, Wp5, Wp6, Wp7, N);
    plan_kernel<<<N / 256, 256, 0, stream>>>(nbr, kmask, cidx, ktab, N);

    blk12_kernel<<<N / 64, 256, 0, stream>>>(x, cat, Wp12, b1, g1, be1, b2, g2, be2);
    conv_kernel<2, 3><<<N / 64, 256, 0, stream>>>(cat, cidx, ktab, kmask, Wp3, b3, g3, be3, 64, 128, N);
    conv_kernel<1, 4><<<N / 64, 256, 0, stream>>>(cat, cidx, ktab, kmask, Wp4, b4, g4, be4, 128, 160, N);
    conv_kernel<1, 4><<<N / 64, 256, 0, stream>>>(cat, cidx, ktab, kmask, Wp5, b5, g5, be5, 160, 192, N);
    conv_kernel<1, 4><<<N / 64, 256, 0, stream>>>(cat, cidx, ktab, kmask, Wp6, b6, g6, be6, 192, 224, N);
    blk7_kernel<<<N / 64, 256, 0, stream>>>(cat, Wp7, b7, g7, be7, (float*)d_out);
}

// Round 13
// 449.003 us; speedup vs baseline: 1.0926x; 1.0116x over previous
//
#include <hip/hip_runtime.h>

typedef __attribute__((ext_vector_type(4))) float  float4_;
typedef __attribute__((ext_vector_type(8))) short  short8;
typedef __attribute__((ext_vector_type(8))) __bf16 bf16x8;
typedef __attribute__((ext_vector_type(4))) unsigned uint4_;

__device__ inline unsigned short f2bf(float f) {
    unsigned u = __builtin_bit_cast(unsigned, f);
    u += 0x7FFFu + ((u >> 16) & 1u);          // round-to-nearest-even
    return (unsigned short)(u >> 16);
}

__device__ inline float4_ mfma16(bf16x8 a, bf16x8 b, float4_ c) {
    return __builtin_amdgcn_mfma_f32_16x16x32_bf16(a, b, c, 0, 0, 0);
}

// ---------------- one merged setup kernel (28 slots: slot 27 all-zero) ---
// packs all weights into B-fragment order + zeroes sentinel row cat[N].
// frag f = (k*ctn + ct)*ntn + nt ; elem = lane*8 + t
// value = W[k][ct*32 + (lane>>4)*8 + t][nt*16 + (lane&15)]
__device__ inline void packW_one(const float* __restrict__ src, unsigned short* __restrict__ dst,
                                 int cin, int cout, int e) {
    int f = e >> 9, i = e & 511, lane = i >> 3, t = i & 7;
    int ntn = cout >> 4, ctn = cin >> 5;
    int nt = f % ntn;
    int rest = f / ntn;
    int ct = rest % ctn;
    int k = rest / ctn;
    int c = ct * 32 + (lane >> 4) * 8 + t;
    int j = nt * 16 + (lane & 15);
    dst[e] = f2bf(src[(k * cin + c) * cout + j]);
}

__global__ void pack_all_kernel(
    const float* __restrict__ W1, const float* __restrict__ W2,
    const float* __restrict__ W3, const float* __restrict__ W4,
    const float* __restrict__ W5, const float* __restrict__ W6,
    const float* __restrict__ W7,
    unsigned short* cat, unsigned short* Wp12, unsigned short* Wp3,
    unsigned short* Wp4, unsigned short* Wp5, unsigned short* Wp6,
    unsigned short* Wp7, int N) {
    int e = blockIdx.x * 256 + threadIdx.x;
    if (e < 8192) {                                  // W1|W2 -> (64,128)
        int f = e >> 9, i = e & 511, lane = i >> 3, t = i & 7;
        int nt = f & 7, ct = f >> 3;
        int c = ct * 32 + (lane >> 4) * 8 + t;
        int j = nt * 16 + (lane & 15);
        float v = (j < 64) ? W1[c * 64 + j] : W2[c * 64 + (j - 64)];
        Wp12[e] = f2bf(v);
        return;
    }
    e -= 8192;
    if (e < 57344) { if (e < 55296) packW_one(W3, Wp3, 64, 32, e); else Wp3[e] = 0; return; }
    e -= 57344;
    if (e < 28672) { if (e < 27648) packW_one(W4, Wp4, 32, 32, e); else Wp4[e] = 0; return; }
    e -= 28672;
    if (e < 28672) { if (e < 27648) packW_one(W5, Wp5, 32, 32, e); else Wp5[e] = 0; return; }
    e -= 28672;
    if (e < 28672) { if (e < 27648) packW_one(W6, Wp6, 32, 32, e); else Wp6[e] = 0; return; }
    e -= 28672;
    if (e < 16384) { packW_one(W7, Wp7, 256, 64, e); return; }
    e -= 16384;
    if (e < 128) ((unsigned*)(cat + (size_t)N * 256))[e] = 0;   // sentinel row
}

// ---------------- plan kernel v5 (r10 verbatim): compacted slot stream ---
// r12 lesson: v7's LDS-staged coalesced output was ~17us SLOWER (56KB LDS
// -> 2 blocks/CU for a streaming kernel). v5's divergent writes were cheap.
// Per 16-row tile t: kmask[t]; cidx[t][j][r] = j-th ACTIVE tap's clamped
// byte offset (j >= c -> sentinel); ktab[t][j] = tap id (27 = zero W).
__global__ __launch_bounds__(256) void plan_kernel(const int* __restrict__ nbr,
                                                   unsigned int* __restrict__ kmask,
                                                   unsigned int* __restrict__ cidx,
                                                   unsigned char* __restrict__ ktab, int N) {
    __shared__ int snb[6912];                        // 256 rows * 27 taps
    __shared__ unsigned tm[16];
    int tid = threadIdx.x;
    if (tid < 16) tm[tid] = 0u;
    __syncthreads();
    long base = (long)blockIdx.x * 6912;
#pragma unroll
    for (int i = 0; i < 27; i++) {
        int j = i * 256 + tid;
        int v = nbr[base + j];
        snb[j] = v;
        if (v >= 0) {
            unsigned r = (unsigned)j / 27u;          // local row 0..255
            unsigned k = (unsigned)j - r * 27u;
            atomicOr(&tm[r >> 4], 1u << k);
        }
    }
    __syncthreads();
    int g = tid >> 4, r = tid & 15;                  // 16 groups x 16 rows
    unsigned m = tm[g];
    int t = blockIdx.x * 16 + g;
    unsigned* cp = cidx + (long)t * 448;
    int j = 0;
#pragma unroll
    for (int k = 0; k < 27; k++) {
        if (m >> k & 1u) {
            int v = snb[(g * 16 + r) * 27 + k];
            cp[j * 16 + r] = (unsigned)(v < 0 ? N : v) * 512u;
            j++;
        }
    }
    for (; j < 28; j++) cp[j * 16 + r] = (unsigned)N * 512u;
    if (r == 0) {
        kmask[t] = m;
        unsigned char* kt = ktab + (long)t * 32;
        int jj = 0;
#pragma unroll
        for (int k = 0; k < 27; k++)
            if (m >> k & 1u) kt[jj++] = (unsigned char)k;
        for (; jj < 32; jj++) kt[jj] = 27;
    }
}

// ---------------- blk1 dual, MT=2: f1|f2 = relu(LN(x@W + b)) -------------
// M-blocked: 32 rows/wave share each weight load (vm-ops/row 2.25 -> 0.63
// for weights). The conv rounds' law: time ~ per-wave vm-op count.
__global__ __launch_bounds__(256) void blk12_kernel(
    const float* __restrict__ x, unsigned short* cat,
    const unsigned short* __restrict__ Wp,
    const float* __restrict__ b1, const float* __restrict__ g1, const float* __restrict__ be1,
    const float* __restrict__ b2, const float* __restrict__ g2, const float* __restrict__ be2) {
    int tid = threadIdx.x, lane = tid & 63, wv = tid >> 6;
    int l15 = lane & 15, q = lane >> 4;
    long base = ((long)blockIdx.x * 4 + wv) * 32;

    float4_ acc[2][8];
#pragma unroll
    for (int mt = 0; mt < 2; mt++)
#pragma unroll
        for (int i = 0; i < 8; i++) acc[mt][i] = (float4_){0.f, 0.f, 0.f, 0.f};

#pragma unroll
    for (int kt = 0; kt < 2; kt++) {
        bf16x8 a[2];
#pragma unroll
        for (int mt = 0; mt < 2; mt++) {
            const float* xp = x + (base + mt * 16 + l15) * 64 + kt * 32 + q * 8;
            float4_ f0 = *(const float4_*)xp;
            float4_ f1 = *(const float4_*)(xp + 4);
            short8 as;
            as[0] = (short)f2bf(f0[0]); as[1] = (short)f2bf(f0[1]);
            as[2] = (short)f2bf(f0[2]); as[3] = (short)f2bf(f0[3]);
            as[4] = (short)f2bf(f1[0]); as[5] = (short)f2bf(f1[1]);
            as[6] = (short)f2bf(f1[2]); as[7] = (short)f2bf(f1[3]);
            a[mt] = __builtin_bit_cast(bf16x8, as);
        }
        const unsigned short* wp = Wp + (size_t)kt * 8 * 512;
#pragma unroll
        for (int nt = 0; nt < 8; nt++) {
            bf16x8 w = *(const bf16x8*)(wp + nt * 512 + lane * 8);
            acc[0][nt] = mfma16(a[0], w, acc[0][nt]);
            acc[1][nt] = mfma16(a[1], w, acc[1][nt]);
        }
    }

    float bc[8], gc[8], bec[8];
#pragma unroll
    for (int nt = 0; nt < 8; nt++) {
        int j = nt * 16 + l15;
        if (j < 64) { bc[nt] = b1[j]; gc[nt] = g1[j]; bec[nt] = be1[j]; }
        else        { bc[nt] = b2[j - 64]; gc[nt] = g2[j - 64]; bec[nt] = be2[j - 64]; }
    }

#pragma unroll
    for (int mt = 0; mt < 2; mt++) {
#pragma unroll
        for (int r = 0; r < 4; r++) {
            long row = base + mt * 16 + q * 4 + r;
            float v[8], s0 = 0.f, s1 = 0.f, q0 = 0.f, q1 = 0.f;
#pragma unroll
            for (int nt = 0; nt < 4; nt++) { v[nt] = acc[mt][nt][r] + bc[nt]; s0 += v[nt]; q0 += v[nt] * v[nt]; }
#pragma unroll
            for (int nt = 4; nt < 8; nt++) { v[nt] = acc[mt][nt][r] + bc[nt]; s1 += v[nt]; q1 += v[nt] * v[nt]; }
#pragma unroll
            for (int mh = 1; mh < 16; mh <<= 1) {
                s0 += __shfl_xor(s0, mh); q0 += __shfl_xor(q0, mh);
                s1 += __shfl_xor(s1, mh); q1 += __shfl_xor(q1, mh);
            }
            float mu0 = s0 * (1.f / 64), var0 = q0 * (1.f / 64) - mu0 * mu0, inv0 = rsqrtf(var0 + 1e-5f);
            float mu1 = s1 * (1.f / 64), var1 = q1 * (1.f / 64) - mu1 * mu1, inv1 = rsqrtf(var1 + 1e-5f);
            unsigned short* cp = cat + row * 256;
#pragma unroll
            for (int nt = 0; nt < 4; nt++) {
                float y = fmaxf((v[nt] - mu0) * inv0 * gc[nt] + bec[nt], 0.f);
                cp[nt * 16 + l15] = f2bf(y);
            }
#pragma unroll
            for (int nt = 4; nt < 8; nt++) {
                float y = fmaxf((v[nt] - mu1) * inv1 * gc[nt] + bec[nt], 0.f);
                cp[nt * 16 + l15] = f2bf(y);
            }
        }
    }
}

// ---------------- sparse conv: r10 branchless compacted core (unchanged) -
template <int CT, int D, int NS>
__device__ __forceinline__ void conv_core(
    float4_ acc[2], const char* catb, const unsigned* cx,
    const unsigned* kt8, const unsigned short* wl) {
    bf16x8 f[D + 1][CT];
    bf16x8 wr[3][CT][2];
    unsigned cv[3];

#define KB(k) ((kt8[(k) >> 2] >> (((k) & 3) * 8)) & 0xFFu)

    unsigned cv0[D + 2];
#pragma unroll
    for (int j = 0; j < D + 2; j++) cv0[j] = cx[j * 16];

#pragma unroll
    for (int kk = 0; kk < 2; kk++) {
        unsigned wo = KB(kk) * (CT * 1024u);
#pragma unroll
        for (int ct = 0; ct < CT; ct++)
#pragma unroll
            for (int nt = 0; nt < 2; nt++)
                wr[kk][ct][nt] = *(const bf16x8*)(wl + wo + (ct * 2 + nt) * 512);
    }

#pragma unroll
    for (int j = 0; j < D; j++) {
#pragma unroll
        for (int ct = 0; ct < CT; ct++)
            f[j][ct] = *(const bf16x8*)(catb + (size_t)cv0[j] + ct * 64);
    }
    cv[D % 3] = cv0[D];
    cv[(D + 1) % 3] = cv0[D + 1];

#pragma unroll
    for (int k = 0; k < NS; k++) {
        if (k + 2 < NS) {                            // weights for slot k+2
            unsigned wo = KB(k + 2) * (CT * 1024u);
#pragma unroll
            for (int ct = 0; ct < CT; ct++)
#pragma unroll
                for (int nt = 0; nt < 2; nt++)
                    wr[(k + 2) % 3][ct][nt] = *(const bf16x8*)(wl + wo + (ct * 2 + nt) * 512);
        }
        if (k + D < NS) {                            // gathers for slot k+D
            unsigned voff = cv[(k + D) % 3];
#pragma unroll
            for (int ct = 0; ct < CT; ct++)
                f[(k + D) % (D + 1)][ct] = *(const bf16x8*)(catb + (size_t)voff + ct * 64);
        }
        if (k + D + 2 < NS) cv[(k + D + 2) % 3] = cx[(k + D + 2) * 16];
#pragma unroll
        for (int ct = 0; ct < CT; ct++) {            // MFMA for slot k
            acc[0] = mfma16(f[k % (D + 1)][ct], wr[k % 3][ct][0], acc[0]);
            acc[1] = mfma16(f[k % (D + 1)][ct], wr[k % 3][ct][1], acc[1]);
        }
    }
#undef KB
}

template <int CT, int D>
__global__ __launch_bounds__(256) void conv_kernel(
    unsigned short* cat, const unsigned int* __restrict__ cidx,
    const unsigned char* __restrict__ ktab,
    const unsigned int* __restrict__ kmask,
    const unsigned short* __restrict__ Wp,
    const float* __restrict__ bb, const float* __restrict__ gg, const float* __restrict__ bee,
    int in_off, int out_off, int N) {
    int tid = threadIdx.x, lane = tid & 63, wv = tid >> 6;
    int l15 = lane & 15, q = lane >> 4;

    // bijective XCD-chunked swizzle (gridDim.x % 8 == 0)
    int cpx = (int)(gridDim.x >> 3);
    int sb = ((int)blockIdx.x & 7) * cpx + ((int)blockIdx.x >> 3);
    int t = sb * 4 + wv;
    long base = (long)t * 16;

    unsigned m = __builtin_amdgcn_readfirstlane(kmask[t]);
    int trips = (__popc(m) + 3) >> 2;                // 1..7 (self tap => c>=1)

    const char* catb = (const char*)cat + (size_t)in_off * 2 + q * 16;
    const unsigned* cx = cidx + (long)t * 448 + l15;
    const unsigned short* wl = Wp + lane * 8;

    uint4_ kv0 = *(const uint4_*)(ktab + (long)t * 32);
    uint4_ kv1 = *(const uint4_*)(ktab + (long)t * 32 + 16);
    unsigned kt8[8] = {kv0[0], kv0[1], kv0[2], kv0[3], kv1[0], kv1[1], kv1[2], kv1[3]};

    float4_ acc[2];
    acc[0] = (float4_){0.f, 0.f, 0.f, 0.f};
    acc[1] = (float4_){0.f, 0.f, 0.f, 0.f};

    switch (trips) {
        case 1: conv_core<CT, D, 4>(acc, catb, cx, kt8, wl); break;
        case 2: conv_core<CT, D, 8>(acc, catb, cx, kt8, wl); break;
        case 3: conv_core<CT, D, 12>(acc, catb, cx, kt8, wl); break;
        case 4: conv_core<CT, D, 16>(acc, catb, cx, kt8, wl); break;
        case 5: conv_core<CT, D, 20>(acc, catb, cx, kt8, wl); break;
        case 6: conv_core<CT, D, 24>(acc, catb, cx, kt8, wl); break;
        default: conv_core<CT, D, 28>(acc, catb, cx, kt8, wl); break;
    }

    // ---- epilogue: bias + LN(32ch) + relu + store ----
    float b0c = bb[l15], b1c = bb[16 + l15];
    float g0c = gg[l15], g1c = gg[16 + l15];
    float be0c = bee[l15], be1c = bee[16 + l15];

#pragma unroll
    for (int r = 0; r < 4; r++) {
        long row = base + q * 4 + r;
        float v0 = acc[0][r] + b0c;
        float v1 = acc[1][r] + b1c;
        float s = v0 + v1, sq = v0 * v0 + v1 * v1;
#pragma unroll
        for (int mh = 1; mh < 16; mh <<= 1) { s += __shfl_xor(s, mh); sq += __shfl_xor(sq, mh); }
        float mu = s * (1.f / 32), var = sq * (1.f / 32) - mu * mu, inv = rsqrtf(var + 1e-5f);
        float y0 = fmaxf((v0 - mu) * inv * g0c + be0c, 0.f);
        float y1 = fmaxf((v1 - mu) * inv * g1c + be1c, 0.f);
        unsigned short* cp = cat + row * 256 + out_off;
        cp[l15] = f2bf(y0);
        cp[16 + l15] = f2bf(y1);
    }
}

// ---------------- final blk1, MT=4: out = relu(LN(cat@W7 + b7)) ----------
// M-blocked: 64 rows/wave share each weight load. vm-ops/row: 2.5 -> 1.0.
__global__ __launch_bounds__(256) void blk7_kernel(
    const unsigned short* __restrict__ cat, const unsigned short* __restrict__ Wp,
    const float* __restrict__ b, const float* __restrict__ g, const float* __restrict__ be,
    float* __restrict__ out) {
    int tid = threadIdx.x, lane = tid & 63, wv = tid >> 6;
    int l15 = lane & 15, q = lane >> 4;
    long base = ((long)blockIdx.x * 4 + wv) * 64;

    float4_ acc[4][4];
#pragma unroll
    for (int mt = 0; mt < 4; mt++)
#pragma unroll
        for (int i = 0; i < 4; i++) acc[mt][i] = (float4_){0.f, 0.f, 0.f, 0.f};

#pragma unroll
    for (int kt = 0; kt < 8; kt++) {
        bf16x8 a[4];
#pragma unroll
        for (int mt = 0; mt < 4; mt++)
            a[mt] = *(const bf16x8*)(cat + (base + mt * 16 + l15) * 256 + kt * 32 + q * 8);
        const unsigned short* wp = Wp + (size_t)kt * 4 * 512;
#pragma unroll
        for (int nt = 0; nt < 4; nt++) {
            bf16x8 w = *(const bf16x8*)(wp + nt * 512 + lane * 8);
#pragma unroll
            for (int mt = 0; mt < 4; mt++)
                acc[mt][nt] = mfma16(a[mt], w, acc[mt][nt]);
        }
    }

    float bc[4], gc[4], bec[4];
#pragma unroll
    for (int nt = 0; nt < 4; nt++) {
        int j = nt * 16 + l15;
        bc[nt] = b[j]; gc[nt] = g[j]; bec[nt] = be[j];
    }

#pragma unroll
    for (int mt = 0; mt < 4; mt++) {
#pragma unroll
        for (int r = 0; r < 4; r++) {
            long row = base + mt * 16 + q * 4 + r;
            float v[4], s = 0.f, sq = 0.f;
#pragma unroll
            for (int nt = 0; nt < 4; nt++) { v[nt] = acc[mt][nt][r] + bc[nt]; s += v[nt]; sq += v[nt] * v[nt]; }
#pragma unroll
            for (int mh = 1; mh < 16; mh <<= 1) { s += __shfl_xor(s, mh); sq += __shfl_xor(sq, mh); }
            float mu = s * (1.f / 64), var = sq * (1.f / 64) - mu * mu, inv = rsqrtf(var + 1e-5f);
#pragma unroll
            for (int nt = 0; nt < 4; nt++) {
                float y = fmaxf((v[nt] - mu) * inv * gc[nt] + bec[nt], 0.f);
                out[row * 64 + nt * 16 + l15] = y;
            }
        }
    }
}

extern "C" void kernel_launch(void* const* d_in, const int* in_sizes, int n_in,
                              void* d_out, int out_size, void* d_ws, size_t ws_size,
                              hipStream_t stream) {
    const int N = in_sizes[0] / 64;   // 262144

    const float* x   = (const float*)d_in[0];
    const int*   nbr = (const int*)d_in[1];
    const float* W1 = (const float*)d_in[2];
    const float* b1 = (const float*)d_in[3];
    const float* g1 = (const float*)d_in[4];
    const float* be1 = (const float*)d_in[5];
    const float* W2 = (const float*)d_in[6];
    const float* b2 = (const float*)d_in[7];
    const float* g2 = (const float*)d_in[8];
    const float* be2 = (const float*)d_in[9];
    const float* W3 = (const float*)d_in[10];
    const float* b3 = (const float*)d_in[11];
    const float* g3 = (const float*)d_in[12];
    const float* be3 = (const float*)d_in[13];
    const float* W4 = (const float*)d_in[14];
    const float* b4 = (const float*)d_in[15];
    const float* g4 = (const float*)d_in[16];
    const float* be4 = (const float*)d_in[17];
    const float* W5 = (const float*)d_in[18];
    const float* b5 = (const float*)d_in[19];
    const float* g5 = (const float*)d_in[20];
    const float* be5 = (const float*)d_in[21];
    const float* W6 = (const float*)d_in[22];
    const float* b6 = (const float*)d_in[23];
    const float* g6 = (const float*)d_in[24];
    const float* be6 = (const float*)d_in[25];
    const float* W7 = (const float*)d_in[26];
    const float* b7 = (const float*)d_in[27];
    const float* g7 = (const float*)d_in[28];
    const float* be7 = (const float*)d_in[29];

    unsigned short* ws   = (unsigned short*)d_ws;
    unsigned short* cat  = ws;                               // (N+1)*256 bf16
    unsigned short* Wp12 = cat + (size_t)(N + 1) * 256;      // 8192
    unsigned short* Wp3  = Wp12 + 8192;                      // 28*2*2*512 = 57344 (slot 27 zero)
    unsigned short* Wp4  = Wp3 + 57344;                      // 28*1*2*512 = 28672
    unsigned short* Wp5  = Wp4 + 28672;
    unsigned short* Wp6  = Wp5 + 28672;
    unsigned short* Wp7  = Wp6 + 28672;                      // 8*4*512 = 16384
    unsigned int*   kmask = (unsigned int*)(Wp7 + 16384);    // N/16 uints
    unsigned int*   cidx  = kmask + N / 16;                  // N/16 * 448 uints
    unsigned char*  ktab  = (unsigned char*)(cidx + (size_t)(N / 16) * 448);  // N/16 * 32 B

    pack_all_kernel<<<657, 256, 0, stream>>>(W1, W2, W3, W4, W5, W6, W7,
                                             cat, Wp12, Wp3, Wp4, Wp5, Wp6, Wp7, N);
    plan_kernel<<<N / 256, 256, 0, stream>>>(nbr, kmask, cidx, ktab, N);

    blk12_kernel<<<N / 128, 256, 0, stream>>>(x, cat, Wp12, b1, g1, be1, b2, g2, be2);
    conv_kernel<2, 3><<<N / 64, 256, 0, stream>>>(cat, cidx, ktab, kmask, Wp3, b3, g3, be3, 64, 128, N);
    conv_kernel<1, 4><<<N / 64, 256, 0, stream>>>(cat, cidx, ktab, kmask, Wp4, b4, g4, be4, 128, 160, N);
    conv_kernel<1, 4><<<N / 64, 256, 0, stream>>>(cat, cidx, ktab, kmask, Wp5, b5, g5, be5, 160, 192, N);
    conv_kernel<1, 4><<<N / 64, 256, 0, stream>>>(cat, cidx, ktab, kmask, Wp6, b6, g6, be6, 192, 224, N);
    blk7_kernel<<<N / 256, 256, 0, stream>>>(cat, Wp7, b7, g7, be7, (float*)d_out);
}

// Round 14
// 434.640 us; speedup vs baseline: 1.1287x; 1.0330x over previous
//
#include <hip/hip_runtime.h>

typedef __attribute__((ext_vector_type(4))) float  float4_;
typedef __attribute__((ext_vector_type(8))) short  short8;
typedef __attribute__((ext_vector_type(8))) __bf16 bf16x8;
typedef __attribute__((ext_vector_type(4))) unsigned uint4_;

__device__ inline unsigned short f2bf(float f) {
    unsigned u = __builtin_bit_cast(unsigned, f);
    u += 0x7FFFu + ((u >> 16) & 1u);          // round-to-nearest-even
    return (unsigned short)(u >> 16);
}

__device__ inline float4_ mfma16(bf16x8 a, bf16x8 b, float4_ c) {
    return __builtin_amdgcn_mfma_f32_16x16x32_bf16(a, b, c, 0, 0, 0);
}

// ---------------- merged setup kernel: pack (blocks 0..656) + plan -------
// pack: weights into B-fragment order (28 slots, slot 27 all-zero) +
//       sentinel row cat[N].
// plan (blocks 657..1680): per 16-row tile t, kmask[t]; compacted
//       cidx[t][j][r] = j-th ACTIVE tap's clamped byte offset (j >= c ->
//       sentinel N*512); ktab[t][j] = tap id (27 = zero-weight block).
// The two halves are data-independent; merging removes one graph node.
__device__ inline void packW_one(const float* __restrict__ src, unsigned short* __restrict__ dst,
                                 int cin, int cout, int e) {
    int f = e >> 9, i = e & 511, lane = i >> 3, t = i & 7;
    int ntn = cout >> 4, ctn = cin >> 5;
    int nt = f % ntn;
    int rest = f / ntn;
    int ct = rest % ctn;
    int k = rest / ctn;
    int c = ct * 32 + (lane >> 4) * 8 + t;
    int j = nt * 16 + (lane & 15);
    dst[e] = f2bf(src[(k * cin + c) * cout + j]);
}

__global__ __launch_bounds__(256) void setup_kernel(
    const float* __restrict__ W1, const float* __restrict__ W2,
    const float* __restrict__ W3, const float* __restrict__ W4,
    const float* __restrict__ W5, const float* __restrict__ W6,
    const float* __restrict__ W7,
    unsigned short* cat, unsigned short* Wp12, unsigned short* Wp3,
    unsigned short* Wp4, unsigned short* Wp5, unsigned short* Wp6,
    unsigned short* Wp7,
    const int* __restrict__ nbr, unsigned int* __restrict__ kmask,
    unsigned int* __restrict__ cidx, unsigned char* __restrict__ ktab, int N) {
    __shared__ int snb[6912];                        // plan path only
    __shared__ unsigned tm[16];
    int tid = threadIdx.x;

    if (blockIdx.x < 657) {                          // ---- pack path ----
        int e = blockIdx.x * 256 + tid;
        if (e < 8192) {                              // W1|W2 -> (64,128)
            int f = e >> 9, i = e & 511, lane = i >> 3, t = i & 7;
            int nt = f & 7, ct = f >> 3;
            int c = ct * 32 + (lane >> 4) * 8 + t;
            int j = nt * 16 + (lane & 15);
            float v = (j < 64) ? W1[c * 64 + j] : W2[c * 64 + (j - 64)];
            Wp12[e] = f2bf(v);
            return;
        }
        e -= 8192;
        if (e < 57344) { if (e < 55296) packW_one(W3, Wp3, 64, 32, e); else Wp3[e] = 0; return; }
        e -= 57344;
        if (e < 28672) { if (e < 27648) packW_one(W4, Wp4, 32, 32, e); else Wp4[e] = 0; return; }
        e -= 28672;
        if (e < 28672) { if (e < 27648) packW_one(W5, Wp5, 32, 32, e); else Wp5[e] = 0; return; }
        e -= 28672;
        if (e < 28672) { if (e < 27648) packW_one(W6, Wp6, 32, 32, e); else Wp6[e] = 0; return; }
        e -= 28672;
        if (e < 16384) { packW_one(W7, Wp7, 256, 64, e); return; }
        e -= 16384;
        if (e < 128) ((unsigned*)(cat + (size_t)N * 256))[e] = 0;   // sentinel row
        return;
    }

    // ---- plan path (r10's v5 verbatim; block id rebased) ----
    int pb = blockIdx.x - 657;
    if (tid < 16) tm[tid] = 0u;
    __syncthreads();
    long base = (long)pb * 6912;
#pragma unroll
    for (int i = 0; i < 27; i++) {
        int j = i * 256 + tid;
        int v = nbr[base + j];
        snb[j] = v;
        if (v >= 0) {
            unsigned r = (unsigned)j / 27u;          // local row 0..255
            unsigned k = (unsigned)j - r * 27u;
            atomicOr(&tm[r >> 4], 1u << k);
        }
    }
    __syncthreads();
    int g = tid >> 4, r = tid & 15;                  // 16 groups x 16 rows
    unsigned m = tm[g];
    int t = pb * 16 + g;
    unsigned* cp = cidx + (long)t * 448;
    int j = 0;
#pragma unroll
    for (int k = 0; k < 27; k++) {
        if (m >> k & 1u) {
            int v = snb[(g * 16 + r) * 27 + k];
            cp[j * 16 + r] = (unsigned)(v < 0 ? N : v) * 512u;
            j++;
        }
    }
    for (; j < 28; j++) cp[j * 16 + r] = (unsigned)N * 512u;
    if (r == 0) {
        kmask[t] = m;
        unsigned char* kt = ktab + (long)t * 32;
        int jj = 0;
#pragma unroll
        for (int k = 0; k < 27; k++)
            if (m >> k & 1u) kt[jj++] = (unsigned char)k;
        for (; jj < 32; jj++) kt[jj] = 27;
    }
}

// ---------------- blk1 dual (r10 MT=1): f1|f2 = relu(LN(x@W + b)) --------
// r13 lesson: M-blocking these regressed (fewer waves cost more in latency
// hiding than amortized weight loads gained). MT=1 restored.
__global__ __launch_bounds__(256) void blk12_kernel(
    const float* __restrict__ x, unsigned short* cat,
    const unsigned short* __restrict__ Wp,
    const float* __restrict__ b1, const float* __restrict__ g1, const float* __restrict__ be1,
    const float* __restrict__ b2, const float* __restrict__ g2, const float* __restrict__ be2) {
    int tid = threadIdx.x, lane = tid & 63, wv = tid >> 6;
    int l15 = lane & 15, q = lane >> 4;
    long base = ((long)blockIdx.x * 4 + wv) * 16;

    float4_ acc[8];
#pragma unroll
    for (int i = 0; i < 8; i++) acc[i] = (float4_){0.f, 0.f, 0.f, 0.f};

#pragma unroll
    for (int kt = 0; kt < 2; kt++) {
        const float* xp = x + (base + l15) * 64 + kt * 32 + q * 8;
        float4_ f0 = *(const float4_*)xp;
        float4_ f1 = *(const float4_*)(xp + 4);
        short8 as;
        as[0] = (short)f2bf(f0[0]); as[1] = (short)f2bf(f0[1]);
        as[2] = (short)f2bf(f0[2]); as[3] = (short)f2bf(f0[3]);
        as[4] = (short)f2bf(f1[0]); as[5] = (short)f2bf(f1[1]);
        as[6] = (short)f2bf(f1[2]); as[7] = (short)f2bf(f1[3]);
        bf16x8 a = __builtin_bit_cast(bf16x8, as);
        const unsigned short* wp = Wp + (size_t)kt * 8 * 512;
#pragma unroll
        for (int nt = 0; nt < 8; nt++) {
            bf16x8 w = *(const bf16x8*)(wp + nt * 512 + lane * 8);
            acc[nt] = mfma16(a, w, acc[nt]);
        }
    }

    float bc[8], gc[8], bec[8];
#pragma unroll
    for (int nt = 0; nt < 8; nt++) {
        int j = nt * 16 + l15;
        if (j < 64) { bc[nt] = b1[j]; gc[nt] = g1[j]; bec[nt] = be1[j]; }
        else        { bc[nt] = b2[j - 64]; gc[nt] = g2[j - 64]; bec[nt] = be2[j - 64]; }
    }

#pragma unroll
    for (int r = 0; r < 4; r++) {
        long row = base + q * 4 + r;
        float v[8], s0 = 0.f, s1 = 0.f, q0 = 0.f, q1 = 0.f;
#pragma unroll
        for (int nt = 0; nt < 4; nt++) { v[nt] = acc[nt][r] + bc[nt]; s0 += v[nt]; q0 += v[nt] * v[nt]; }
#pragma unroll
        for (int nt = 4; nt < 8; nt++) { v[nt] = acc[nt][r] + bc[nt]; s1 += v[nt]; q1 += v[nt] * v[nt]; }
#pragma unroll
        for (int m = 1; m < 16; m <<= 1) {
            s0 += __shfl_xor(s0, m); q0 += __shfl_xor(q0, m);
            s1 += __shfl_xor(s1, m); q1 += __shfl_xor(q1, m);
        }
        float mu0 = s0 * (1.f / 64), var0 = q0 * (1.f / 64) - mu0 * mu0, inv0 = rsqrtf(var0 + 1e-5f);
        float mu1 = s1 * (1.f / 64), var1 = q1 * (1.f / 64) - mu1 * mu1, inv1 = rsqrtf(var1 + 1e-5f);
        unsigned short* cp = cat + row * 256;
#pragma unroll
        for (int nt = 0; nt < 4; nt++) {
            float y = fmaxf((v[nt] - mu0) * inv0 * gc[nt] + bec[nt], 0.f);
            cp[nt * 16 + l15] = f2bf(y);
        }
#pragma unroll
        for (int nt = 4; nt < 8; nt++) {
            float y = fmaxf((v[nt] - mu1) * inv1 * gc[nt] + bec[nt], 0.f);
            cp[nt * 16 + l15] = f2bf(y);
        }
    }
}

// ---------------- sparse conv: r10 branchless compacted core (unchanged) -
template <int CT, int D, int NS>
__device__ __forceinline__ void conv_core(
    float4_ acc[2], const char* catb, const unsigned* cx,
    const unsigned* kt8, const unsigned short* wl) {
    bf16x8 f[D + 1][CT];
    bf16x8 wr[3][CT][2];
    unsigned cv[3];

#define KB(k) ((kt8[(k) >> 2] >> (((k) & 3) * 8)) & 0xFFu)

    unsigned cv0[D + 2];
#pragma unroll
    for (int j = 0; j < D + 2; j++) cv0[j] = cx[j * 16];

#pragma unroll
    for (int kk = 0; kk < 2; kk++) {
        unsigned wo = KB(kk) * (CT * 1024u);
#pragma unroll
        for (int ct = 0; ct < CT; ct++)
#pragma unroll
            for (int nt = 0; nt < 2; nt++)
                wr[kk][ct][nt] = *(const bf16x8*)(wl + wo + (ct * 2 + nt) * 512);
    }

#pragma unroll
    for (int j = 0; j < D; j++) {
#pragma unroll
        for (int ct = 0; ct < CT; ct++)
            f[j][ct] = *(const bf16x8*)(catb + (size_t)cv0[j] + ct * 64);
    }
    cv[D % 3] = cv0[D];
    cv[(D + 1) % 3] = cv0[D + 1];

#pragma unroll
    for (int k = 0; k < NS; k++) {
        if (k + 2 < NS) {                            // weights for slot k+2
            unsigned wo = KB(k + 2) * (CT * 1024u);
#pragma unroll
            for (int ct = 0; ct < CT; ct++)
#pragma unroll
                for (int nt = 0; nt < 2; nt++)
                    wr[(k + 2) % 3][ct][nt] = *(const bf16x8*)(wl + wo + (ct * 2 + nt) * 512);
        }
        if (k + D < NS) {                            // gathers for slot k+D
            unsigned voff = cv[(k + D) % 3];
#pragma unroll
            for (int ct = 0; ct < CT; ct++)
                f[(k + D) % (D + 1)][ct] = *(const bf16x8*)(catb + (size_t)voff + ct * 64);
        }
        if (k + D + 2 < NS) cv[(k + D + 2) % 3] = cx[(k + D + 2) * 16];
#pragma unroll
        for (int ct = 0; ct < CT; ct++) {            // MFMA for slot k
            acc[0] = mfma16(f[k % (D + 1)][ct], wr[k % 3][ct][0], acc[0]);
            acc[1] = mfma16(f[k % (D + 1)][ct], wr[k % 3][ct][1], acc[1]);
        }
    }
#undef KB
}

template <int CT, int D>
__global__ __launch_bounds__(256) void conv_kernel(
    unsigned short* cat, const unsigned int* __restrict__ cidx,
    const unsigned char* __restrict__ ktab,
    const unsigned int* __restrict__ kmask,
    const unsigned short* __restrict__ Wp,
    const float* __restrict__ bb, const float* __restrict__ gg, const float* __restrict__ bee,
    int in_off, int out_off, int N) {
    int tid = threadIdx.x, lane = tid & 63, wv = tid >> 6;
    int l15 = lane & 15, q = lane >> 4;

    // bijective XCD-chunked swizzle (gridDim.x % 8 == 0)
    int cpx = (int)(gridDim.x >> 3);
    int sb = ((int)blockIdx.x & 7) * cpx + ((int)blockIdx.x >> 3);
    int t = sb * 4 + wv;
    long base = (long)t * 16;

    unsigned m = __builtin_amdgcn_readfirstlane(kmask[t]);
    int trips = (__popc(m) + 3) >> 2;                // 1..7 (self tap => c>=1)

    const char* catb = (const char*)cat + (size_t)in_off * 2 + q * 16;
    const unsigned* cx = cidx + (long)t * 448 + l15;
    const unsigned short* wl = Wp + lane * 8;

    uint4_ kv0 = *(const uint4_*)(ktab + (long)t * 32);
    uint4_ kv1 = *(const uint4_*)(ktab + (long)t * 32 + 16);
    unsigned kt8[8] = {kv0[0], kv0[1], kv0[2], kv0[3], kv1[0], kv1[1], kv1[2], kv1[3]};

    float4_ acc[2];
    acc[0] = (float4_){0.f, 0.f, 0.f, 0.f};
    acc[1] = (float4_){0.f, 0.f, 0.f, 0.f};

    switch (trips) {
        case 1: conv_core<CT, D, 4>(acc, catb, cx, kt8, wl); break;
        case 2: conv_core<CT, D, 8>(acc, catb, cx, kt8, wl); break;
        case 3: conv_core<CT, D, 12>(acc, catb, cx, kt8, wl); break;
        case 4: conv_core<CT, D, 16>(acc, catb, cx, kt8, wl); break;
        case 5: conv_core<CT, D, 20>(acc, catb, cx, kt8, wl); break;
        case 6: conv_core<CT, D, 24>(acc, catb, cx, kt8, wl); break;
        default: conv_core<CT, D, 28>(acc, catb, cx, kt8, wl); break;
    }

    // ---- epilogue: bias + LN(32ch) + relu + store ----
    float b0c = bb[l15], b1c = bb[16 + l15];
    float g0c = gg[l15], g1c = gg[16 + l15];
    float be0c = bee[l15], be1c = bee[16 + l15];

#pragma unroll
    for (int r = 0; r < 4; r++) {
        long row = base + q * 4 + r;
        float v0 = acc[0][r] + b0c;
        float v1 = acc[1][r] + b1c;
        float s = v0 + v1, sq = v0 * v0 + v1 * v1;
#pragma unroll
        for (int mh = 1; mh < 16; mh <<= 1) { s += __shfl_xor(s, mh); sq += __shfl_xor(sq, mh); }
        float mu = s * (1.f / 32), var = sq * (1.f / 32) - mu * mu, inv = rsqrtf(var + 1e-5f);
        float y0 = fmaxf((v0 - mu) * inv * g0c + be0c, 0.f);
        float y1 = fmaxf((v1 - mu) * inv * g1c + be1c, 0.f);
        unsigned short* cp = cat + row * 256 + out_off;
        cp[l15] = f2bf(y0);
        cp[16 + l15] = f2bf(y1);
    }
}

// ---------------- final blk1 (r10 MT=1): out = relu(LN(cat@W7 + b7)) -----
__global__ __launch_bounds__(256) void blk7_kernel(
    const unsigned short* __restrict__ cat, const unsigned short* __restrict__ Wp,
    const float* __restrict__ b, const float* __restrict__ g, const float* __restrict__ be,
    float* __restrict__ out) {
    int tid = threadIdx.x, lane = tid & 63, wv = tid >> 6;
    int l15 = lane & 15, q = lane >> 4;
    long base = ((long)blockIdx.x * 4 + wv) * 16;

    float4_ acc[4];
#pragma unroll
    for (int i = 0; i < 4; i++) acc[i] = (float4_){0.f, 0.f, 0.f, 0.f};

#pragma unroll
    for (int kt = 0; kt < 8; kt++) {
        bf16x8 a = *(const bf16x8*)(cat + (base + l15) * 256 + kt * 32 + q * 8);
        const unsigned short* wp = Wp + (size_t)kt * 4 * 512;
#pragma unroll
        for (int nt = 0; nt < 4; nt++) {
            bf16x8 w = *(const bf16x8*)(wp + nt * 512 + lane * 8);
            acc[nt] = mfma16(a, w, acc[nt]);
        }
    }

    float bc[4], gc[4], bec[4];
#pragma unroll
    for (int nt = 0; nt < 4; nt++) {
        int j = nt * 16 + l15;
        bc[nt] = b[j]; gc[nt] = g[j]; bec[nt] = be[j];
    }

#pragma unroll
    for (int r = 0; r < 4; r++) {
        long row = base + q * 4 + r;
        float v[4], s = 0.f, sq = 0.f;
#pragma unroll
        for (int nt = 0; nt < 4; nt++) { v[nt] = acc[nt][r] + bc[nt]; s += v[nt]; sq += v[nt] * v[nt]; }
#pragma unroll
        for (int m = 1; m < 16; m <<= 1) { s += __shfl_xor(s, m); sq += __shfl_xor(sq, m); }
        float mu = s * (1.f / 64), var = sq * (1.f / 64) - mu * mu, inv = rsqrtf(var + 1e-5f);
#pragma unroll
        for (int nt = 0; nt < 4; nt++) {
            float y = fmaxf((v[nt] - mu) * inv * gc[nt] + bec[nt], 0.f);
            out[row * 64 + nt * 16 + l15] = y;
        }
    }
}

extern "C" void kernel_launch(void* const* d_in, const int* in_sizes, int n_in,
                              void* d_out, int out_size, void* d_ws, size_t ws_size,
                              hipStream_t stream) {
    const int N = in_sizes[0] / 64;   // 262144

    const float* x   = (const float*)d_in[0];
    const int*   nbr = (const int*)d_in[1];
    const float* W1 = (const float*)d_in[2];
    const float* b1 = (const float*)d_in[3];
    const float* g1 = (const float*)d_in[4];
    const float* be1 = (const float*)d_in[5];
    const float* W2 = (const float*)d_in[6];
    const float* b2 = (const float*)d_in[7];
    const float* g2 = (const float*)d_in[8];
    const float* be2 = (const float*)d_in[9];
    const float* W3 = (const float*)d_in[10];
    const float* b3 = (const float*)d_in[11];
    const float* g3 = (const float*)d_in[12];
    const float* be3 = (const float*)d_in[13];
    const float* W4 = (const float*)d_in[14];
    const float* b4 = (const float*)d_in[15];
    const float* g4 = (const float*)d_in[16];
    const float* be4 = (const float*)d_in[17];
    const float* W5 = (const float*)d_in[18];
    const float* b5 = (const float*)d_in[19];
    const float* g5 = (const float*)d_in[20];
    const float* be5 = (const float*)d_in[21];
    const float* W6 = (const float*)d_in[22];
    const float* b6 = (const float*)d_in[23];
    const float* g6 = (const float*)d_in[24];
    const float* be6 = (const float*)d_in[25];
    const float* W7 = (const float*)d_in[26];
    const float* b7 = (const float*)d_in[27];
    const float* g7 = (const float*)d_in[28];
    const float* be7 = (const float*)d_in[29];

    unsigned short* ws   = (unsigned short*)d_ws;
    unsigned short* cat  = ws;                               // (N+1)*256 bf16
    unsigned short* Wp12 = cat + (size_t)(N + 1) * 256;      // 8192
    unsigned short* Wp3  = Wp12 + 8192;                      // 28*2*2*512 = 57344 (slot 27 zero)
    unsigned short* Wp4  = Wp3 + 57344;                      // 28*1*2*512 = 28672
    unsigned short* Wp5  = Wp4 + 28672;
    unsigned short* Wp6  = Wp5 + 28672;
    unsigned short* Wp7  = Wp6 + 28672;                      // 8*4*512 = 16384
    unsigned int*   kmask = (unsigned int*)(Wp7 + 16384);    // N/16 uints
    unsigned int*   cidx  = kmask + N / 16;                  // N/16 * 448 uints
    unsigned char*  ktab  = (unsigned char*)(cidx + (size_t)(N / 16) * 448);  // N/16 * 32 B

    setup_kernel<<<657 + N / 256, 256, 0, stream>>>(W1, W2, W3, W4, W5, W6, W7,
                                                    cat, Wp12, Wp3, Wp4, Wp5, Wp6, Wp7,
                                                    nbr, kmask, cidx, ktab, N);

    blk12_kernel<<<N / 64, 256, 0, stream>>>(x, cat, Wp12, b1, g1, be1, b2, g2, be2);
    conv_kernel<2, 3><<<N / 64, 256, 0, stream>>>(cat, cidx, ktab, kmask, Wp3, b3, g3, be3, 64, 128, N);
    conv_kernel<1, 4><<<N / 64, 256, 0, stream>>>(cat, cidx, ktab, kmask, Wp4, b4, g4, be4, 128, 160, N);
    conv_kernel<1, 4><<<N / 64, 256, 0, stream>>>(cat, cidx, ktab, kmask, Wp5, b5, g5, be5, 160, 192, N);
    conv_kernel<1, 4><<<N / 64, 256, 0, stream>>>(cat, cidx, ktab, kmask, Wp6, b6, g6, be6, 192, 224, N);
    blk7_kernel<<<N / 64, 256, 0, stream>>>(cat, Wp7, b7, g7, be7, (float*)d_out);
}